// Round 19
// baseline (263.037 us; speedup 1.0000x reference)
//
#include <hip/hip_runtime.h>
#include <hip/hip_fp16.h>

#define EPS 1e-5f

typedef _Float16 f16x8 __attribute__((ext_vector_type(8)));
typedef float f32x4 __attribute__((ext_vector_type(4)));
typedef __attribute__((address_space(3))) uint32_t lds_u32;
typedef const __attribute__((address_space(1))) uint32_t glb_u32;

// ---- ws layout (halfs): 158,821,632 B ----
#define WFHT_OFF 0ull               // [kstep32 1936][o 128][kl 32]
#define W2P_OFF 7929856ull          // [kk 18][g 4][co 64][kl8], BN-pre-scaled
#define W3Q_OFF 7966720ull          // [kk 18][g 4][co 128][kl8], BN-pre-scaled
#define H3_OFF  8040448ull          // 1152 x 61952, per patch [co 128][pix 484]
#define FOLD_OFF 79409152ull        // float: [0,576) w1f | [576,640) sh1
                                    // | [640,704) sh2 | [704,832) sh3

__device__ __forceinline__ uint32_t pk2(float a, float b) {
    __half2 h = __floats2half2_rn(a, b);
    return *reinterpret_cast<uint32_t*>(&h);
}

// ---------------- prep: weight repacks (BN-folded) + bias-init (R18, proven) ----------------
__global__ __launch_bounds__(256)
void k_prep(const float* __restrict__ w1, const float* __restrict__ b1,
            const float* __restrict__ g1, const float* __restrict__ be1,
            const float* __restrict__ m1, const float* __restrict__ v1,
            const float* __restrict__ w2, const float* __restrict__ b2,
            const float* __restrict__ g2, const float* __restrict__ be2,
            const float* __restrict__ m2, const float* __restrict__ v2,
            const float* __restrict__ w3, const float* __restrict__ b3,
            const float* __restrict__ g3, const float* __restrict__ be3,
            const float* __restrict__ m3, const float* __restrict__ v3,
            const float* __restrict__ wf, const float* __restrict__ bf,
            __half* __restrict__ ws, float* __restrict__ out)
{
    const int i = blockIdx.x * 256 + threadIdx.x;
    float* fold = reinterpret_cast<float*>(ws + FOLD_OFF);
    if (i < 247808) {                         // wfhT: 1936 ks x 128 o (FC k = wf linear)
        const int ks = i >> 7, o = i & 127;
        uint2 pk[8];
        if (o < 100) {
            const float* src = wf + (size_t)o * 61952 + ks * 32;
            #pragma unroll
            for (int t = 0; t < 8; ++t) {
                const float4 f = *reinterpret_cast<const float4*>(src + 4 * t);
                pk[t] = make_uint2(pk2(f.x, f.y), pk2(f.z, f.w));
            }
        } else {
            #pragma unroll
            for (int t = 0; t < 8; ++t) pk[t] = make_uint2(0u, 0u);
        }
        uint2* dst = reinterpret_cast<uint2*>(ws + WFHT_OFF + (size_t)i * 32);
        #pragma unroll
        for (int t = 0; t < 8; ++t) dst[t] = pk[t];
    } else if (i < 284672) {                  // w2p[kk][g][co64][kl8] * sc2
        const int j = i - 247808;
        const int kk = j >> 11, s = j & 2047;
        const int gg = s >> 9, co = (s >> 3) & 63, kl8 = s & 7;
        const int tap = kk >> 1, ci = (kk & 1) * 32 + gg * 8 + kl8;
        const float sc = g2[co] * rsqrtf(v2[co] + EPS);
        ws[W2P_OFF + j] = __float2half(w2[co * 576 + ci * 9 + tap] * sc);
    } else if (i < 358400) {                  // w3q[kk][g][co128][kl8] * sc3
        const int j = i - 284672;
        const int kk = j >> 12, s = j & 4095;
        const int gg = s >> 10, co = (s >> 3) & 127, kl8 = s & 7;
        const int tap = kk >> 1, ci = (kk & 1) * 32 + gg * 8 + kl8;
        const float sc = g3[co] * rsqrtf(v3[co] + EPS);
        ws[W3Q_OFF + j] = __float2half(w3[co * 576 + ci * 9 + tap] * sc);
    } else if (i < 473600) {                  // out = bias
        const int j = i - 358400;
        out[j] = bf[j % 100];
    } else if (i < 474432) {                  // fold region
        const int j = i - 473600;
        if (j < 576) {
            const int co = j / 9;
            fold[j] = w1[j] * (g1[co] * rsqrtf(v1[co] + EPS));
        } else if (j < 640) {
            const int co = j - 576;
            const float sc = g1[co] * rsqrtf(v1[co] + EPS);
            fold[j] = be1[co] - (m1[co] - b1[co]) * sc;
        } else if (j < 704) {
            const int co = j - 640;
            const float sc = g2[co] * rsqrtf(v2[co] + EPS);
            fold[j] = be2[co] - (m2[co] - b2[co]) * sc;
        } else {
            const int co = j - 704;
            const float sc = g3[co] * rsqrtf(v3[co] + EPS);
            fold[j] = be3[co] - (m3[co] - b3[co]) * sc;
        }
    }
}

// act: 128-B rows (64 fp16), 16B-granule XOR on (row&7)
__device__ __forceinline__ int lds128(int row, int colByte) {
    return row * 128 + (colByte ^ ((row & 7) << 4));
}

// ---------------- fused conv1 -> conv2 -> conv3 (R18, proven 155 us) ----------------
__global__ __launch_bounds__(512, 4)
void k_conv123(const float* __restrict__ x, const __half* __restrict__ ws_c,
               __half* __restrict__ ws)
{
    __shared__ char smem[76400];
    float* patch = reinterpret_cast<float*>(smem);   // 1904 B
    char* act = smem + 1904;                         // 390 x 128 B -> ends 51824
    char* wbuf = smem + 51824;                       // 3 x 8192 B

    const int bid = blockIdx.x;
    const int p = bid >> 1, half = bid & 1;
    const int tid = threadIdx.x, lane = tid & 63, wave = tid >> 6;
    const int l15 = lane & 15, g = lane >> 4;
    const int wm = wave >> 1, wn = wave & 1;
    const int base3 = half * 11;
    const float* fold = reinterpret_cast<const float*>(ws_c + FOLD_OFF);

    // ---- patchify
    {
        const int b = p / 9, r9 = p - b * 9, hb = r9 / 3, wb = r9 - hb * 3;
        const float* xb = x + (size_t)b * 7056 + (hb * 28 + base3) * 84 + wb * 28;
        if (tid < 476) patch[tid] = xb[(tid / 28) * 84 + (tid % 28)];
    }
    __syncthreads();

    // ---- conv1: sliding 3x3 window
    {
        const int co = lane;
        float wr[9];
        #pragma unroll
        for (int t = 0; t < 9; ++t) wr[t] = fold[co * 9 + t];
        const float sh = fold[576 + co];
        #pragma unroll
        for (int rr = 0; rr < 2; ++rr) {
            const int r = wave * 2 + rr;
            if (r < 15) {
                const float* prow = patch + r * 28;
                float a0 = prow[0], a1 = prow[28], a2 = prow[56];
                float b0 = prow[1], b1 = prow[29], b2 = prow[57];
                for (int xp = 0; xp < 13; ++xp) {
                    const int xx = xp * 2;
                    const float2 c0 = *reinterpret_cast<const float2*>(prow + xx + 2);
                    const float2 c1 = *reinterpret_cast<const float2*>(prow + xx + 30);
                    const float2 c2 = *reinterpret_cast<const float2*>(prow + xx + 58);
                    float s = a0 * wr[0] + b0 * wr[1] + c0.x * wr[2]
                            + a1 * wr[3] + b1 * wr[4] + c1.x * wr[5]
                            + a2 * wr[6] + b2 * wr[7] + c2.x * wr[8];
                    *reinterpret_cast<__half*>(act + lds128(r * 26 + xx, co * 2)) =
                        __float2half(fmaxf(s + sh, 0.f));
                    s = b0 * wr[0] + c0.x * wr[1] + c0.y * wr[2]
                      + b1 * wr[3] + c1.x * wr[4] + c1.y * wr[5]
                      + b2 * wr[6] + c2.x * wr[7] + c2.y * wr[8];
                    *reinterpret_cast<__half*>(act + lds128(r * 26 + xx + 1, co * 2)) =
                        __float2half(fmaxf(s + sh, 0.f));
                    a0 = c0.x; a1 = c1.x; a2 = c2.x;
                    b0 = c0.y; b1 = c1.y; b2 = c2.y;
                }
            }
        }
    }
    __syncthreads();

    const __half* w2q = ws_c + W2P_OFF;
    const __half* w3q = ws_c + W3Q_OFF;

    // ---- conv2 (staged): M=312 -> 20 tiles (5/wm); 2 ct per wn. 9 tap-stages.
    int rb2[5];
    #pragma unroll
    for (int t = 0; t < 5; ++t) {
        int m = (wm * 5 + t) * 16 + l15;
        if (m > 311) m = 311;
        const int yy = m / 24, xx = m - yy * 24;
        rb2[t] = yy * 26 + xx;
    }
    f32x4 acc2[5][2];
    #pragma unroll
    for (int t = 0; t < 5; ++t)
        #pragma unroll
        for (int ct = 0; ct < 2; ++ct) acc2[t][ct] = (f32x4)0.f;

    {
        const int w2off = g * 1024 + (wn * 32 + l15) * 16;
        #define STG2(TAP)                                                          \
            __builtin_amdgcn_global_load_lds(                                      \
                (glb_u32*)(w2q + (TAP) * 4096 + wave * 512 + lane * 8),            \
                (lds_u32*)(wbuf + ((TAP) % 3) * 8192 + wave * 1024), 16, 0, 0)
        STG2(0); STG2(1); STG2(2);
        #pragma unroll
        for (int tap = 0; tap < 9; ++tap) {
            if (tap == 0)      asm volatile("s_waitcnt vmcnt(2)" ::: "memory");
            else if (tap < 8)  asm volatile("s_waitcnt vmcnt(1)" ::: "memory");
            else               asm volatile("s_waitcnt vmcnt(0)" ::: "memory");
            __builtin_amdgcn_sched_barrier(0);
            __builtin_amdgcn_s_barrier();
            __builtin_amdgcn_sched_barrier(0);
            if (tap >= 1 && tap <= 6) STG2(tap + 2);
            const char* sb = wbuf + (tap % 3) * 8192;
            const int ro = (tap / 3) * 26 + (tap % 3);
            int ad[5];
            #pragma unroll
            for (int t = 0; t < 5; ++t) ad[t] = lds128(rb2[t] + ro, g * 16);
            #pragma unroll
            for (int par = 0; par < 2; ++par) {
                const f16x8 wv0 = *reinterpret_cast<const f16x8*>(sb + par * 4096 + w2off);
                const f16x8 wv1 = *reinterpret_cast<const f16x8*>(sb + par * 4096 + w2off + 256);
                #pragma unroll
                for (int t = 0; t < 5; ++t) {
                    const f16x8 af = *reinterpret_cast<const f16x8*>(act + (ad[t] ^ (par * 64)));
                    acc2[t][0] = __builtin_amdgcn_mfma_f32_16x16x32_f16(wv0, af, acc2[t][0], 0, 0, 0);
                    acc2[t][1] = __builtin_amdgcn_mfma_f32_16x16x32_f16(wv1, af, acc2[t][1], 0, 0, 0);
                }
            }
        }
        #undef STG2
    }
    __syncthreads();

    // ---- h2 epilogue
    {
        #pragma unroll
        for (int ct = 0; ct < 2; ++ct) {
            const int co0 = wn * 32 + ct * 16 + g * 4;
            const float4 sh4 = *reinterpret_cast<const float4*>(fold + 640 + co0);
            #pragma unroll
            for (int t = 0; t < 5; ++t) {
                const int m = (wm * 5 + t) * 16 + l15;
                if (m < 312) {
                    const float v0 = fmaxf(acc2[t][ct][0] + sh4.x, 0.f);
                    const float v1 = fmaxf(acc2[t][ct][1] + sh4.y, 0.f);
                    const float v2_ = fmaxf(acc2[t][ct][2] + sh4.z, 0.f);
                    const float v3_ = fmaxf(acc2[t][ct][3] + sh4.w, 0.f);
                    *reinterpret_cast<uint2*>(
                        act + lds128(m, wn * 64 + ct * 32 + g * 8)) =
                        make_uint2(pk2(v0, v1), pk2(v2_, v3_));
                }
            }
        }
    }
    __syncthreads();

    // ---- conv3 (staged per kk)
    int rb3[4];
    #pragma unroll
    for (int t = 0; t < 4; ++t) {
        int m = (wm * 4 + t) * 16 + l15;
        if (m > 241) m = 241;
        const int yy = m / 22, xx = m - yy * 22;
        rb3[t] = yy * 24 + xx;
    }
    f32x4 acc3[4][4];
    #pragma unroll
    for (int t = 0; t < 4; ++t)
        #pragma unroll
        for (int ct = 0; ct < 4; ++ct) acc3[t][ct] = (f32x4)0.f;

    {
        const int w3off = g * 2048 + (wn * 64 + l15) * 16;
        #define STG3(KK)                                                           \
            __builtin_amdgcn_global_load_lds(                                      \
                (glb_u32*)(w3q + (KK) * 4096 + wave * 512 + lane * 8),             \
                (lds_u32*)(wbuf + ((KK) % 3) * 8192 + wave * 1024), 16, 0, 0)
        STG3(0); STG3(1); STG3(2);
        #pragma unroll
        for (int tap = 0; tap < 9; ++tap) {
            const int ro = (tap / 3) * 24 + (tap % 3);
            int ad[4];
            #pragma unroll
            for (int t = 0; t < 4; ++t) ad[t] = lds128(rb3[t] + ro, g * 16);
            #pragma unroll
            for (int par = 0; par < 2; ++par) {
                const int kk = tap * 2 + par;
                if (kk == 0)       asm volatile("s_waitcnt vmcnt(2)" ::: "memory");
                else if (kk < 17)  asm volatile("s_waitcnt vmcnt(1)" ::: "memory");
                else               asm volatile("s_waitcnt vmcnt(0)" ::: "memory");
                __builtin_amdgcn_sched_barrier(0);
                __builtin_amdgcn_s_barrier();
                __builtin_amdgcn_sched_barrier(0);
                if (kk >= 1 && kk <= 15) STG3(kk + 2);
                const char* sb = wbuf + (kk % 3) * 8192;
                f16x8 wv[4];
                #pragma unroll
                for (int ct = 0; ct < 4; ++ct)
                    wv[ct] = *reinterpret_cast<const f16x8*>(sb + w3off + ct * 256);
                const int px = par * 64;
                #pragma unroll
                for (int t = 0; t < 4; ++t) {
                    const f16x8 af = *reinterpret_cast<const f16x8*>(act + (ad[t] ^ px));
                    #pragma unroll
                    for (int ct = 0; ct < 4; ++ct)
                        acc3[t][ct] = __builtin_amdgcn_mfma_f32_16x16x32_f16(
                            wv[ct], af, acc3[t][ct], 0, 0, 0);
                }
            }
        }
        #undef STG3
    }

    // ---- h3 epilogue
    {
        __half* slot = ws + H3_OFF + (size_t)p * 61952;
        #pragma unroll
        for (int ct = 0; ct < 4; ++ct) {
            const int co0 = wn * 64 + ct * 16 + g * 4;
            const float4 sh4 = *reinterpret_cast<const float4*>(fold + 704 + co0);
            #pragma unroll
            for (int t = 0; t < 4; ++t) {
                const int m = (wm * 4 + t) * 16 + l15;
                if (m < 242) {
                    const int pixg = 242 * half + m;
                    slot[(size_t)(co0 + 0) * 484 + pixg] =
                        __float2half(fmaxf(acc3[t][ct][0] + sh4.x, 0.f));
                    slot[(size_t)(co0 + 1) * 484 + pixg] =
                        __float2half(fmaxf(acc3[t][ct][1] + sh4.y, 0.f));
                    slot[(size_t)(co0 + 2) * 484 + pixg] =
                        __float2half(fmaxf(acc3[t][ct][2] + sh4.z, 0.f));
                    slot[(size_t)(co0 + 3) * 484 + pixg] =
                        __float2half(fmaxf(acc3[t][ct][3] + sh4.w, 0.f));
                }
            }
        }
    }
}

// ---------------- FC v3: M=128, kc=88, XCD-clustered kc (L2-resident wfhT) ----------------
// 792 blocks = 8 XCDs x 99; swz wgid=(bid%8)*99+bid/8 clusters 11 consecutive kc
// per XCD -> that XCD's wfhT slice (1.5 MB) stays L2-resident across its 9 mb
// blocks. M-tile 128 halves B-read multiplicity (18 -> 9).
__global__ __launch_bounds__(256)
void k_fc(const __half* __restrict__ ws, float* __restrict__ out)
{
    const __half* h3 = ws + H3_OFF;
    __shared__ char As[2][16384];          // [128 rows][128 B], XOR-swizzled

    const int bid0 = blockIdx.x;           // 792 = 8 * 99
    const int wgid = (bid0 & 7) * 99 + (bid0 >> 3);
    const int mb = wgid % 9, kc = wgid / 9;     // kc in [0,88)
    const int tid = threadIdx.x, lane = tid & 63, wave = tid >> 6;
    const int wm = wave >> 1, wn = wave & 1;
    const int l15 = lane & 15, g = lane >> 4;

    const size_t kbase = (size_t)kc * 704;      // 704 halfs = 22 k-steps of 32

    // staging: thread covers rows (tid>>3)+32p, 16 B at (tid&7)*16; 4 passes
    const int srow = tid >> 3;             // 0..31
    const int scolB = (tid & 7) * 16;      // 0..112
    const __half* sbase = h3 + (size_t)(mb * 128) * 61952 + kbase + (tid & 7) * 8;

    const __half* Bp[4];
    #pragma unroll
    for (int nt = 0; nt < 4; ++nt)
        Bp[nt] = ws + WFHT_OFF + (size_t)(kc * 22) * 4096
               + (size_t)(wn * 64 + nt * 16 + l15) * 32 + g * 8;

    f32x4 acc[4][4];
    #pragma unroll
    for (int mt = 0; mt < 4; ++mt)
        #pragma unroll
        for (int nt = 0; nt < 4; ++nt) acc[mt][nt] = (f32x4)0.f;

    // prologue: stage step 0
    {
        uint4 sv[4];
        #pragma unroll
        for (int pp = 0; pp < 4; ++pp)
            sv[pp] = *reinterpret_cast<const uint4*>(sbase + (size_t)(pp * 32 + srow) * 61952);
        #pragma unroll
        for (int pp = 0; pp < 4; ++pp) {
            const int row = pp * 32 + srow;
            *reinterpret_cast<uint4*>(As[0] + row * 128 + (scolB ^ ((row & 7) << 4))) = sv[pp];
        }
    }

    for (int s = 0; s < 11; ++s) {
        __syncthreads();   // stage(s) visible; compute(s-1) reads done

        uint4 sv[4];
        const int nb = (s + 1) & 1;
        if (s < 10) {      // issue next-step loads early
            #pragma unroll
            for (int pp = 0; pp < 4; ++pp)
                sv[pp] = *reinterpret_cast<const uint4*>(
                    sbase + (size_t)(pp * 32 + srow) * 61952 + (s + 1) * 64);
        }

        const char* Ab = As[s & 1];
        #pragma unroll
        for (int kk = 0; kk < 2; ++kk) {       // 2 k-steps per super-step
            f16x8 a[4];
            #pragma unroll
            for (int mt = 0; mt < 4; ++mt) {
                const int row = wm * 64 + mt * 16 + l15;
                a[mt] = *reinterpret_cast<const f16x8*>(
                    Ab + row * 128 + ((kk * 64 + g * 16) ^ ((row & 7) << 4)));
            }
            f16x8 b[4];
            #pragma unroll
            for (int nt = 0; nt < 4; ++nt)
                b[nt] = *reinterpret_cast<const f16x8*>(Bp[nt] + (s * 2 + kk) * 4096);
            #pragma unroll
            for (int nt = 0; nt < 4; ++nt)
                #pragma unroll
                for (int mt = 0; mt < 4; ++mt)
                    acc[mt][nt] = __builtin_amdgcn_mfma_f32_16x16x32_f16(
                        a[mt], b[nt], acc[mt][nt], 0, 0, 0);
        }

        if (s < 10) {      // write-late into the other buffer
            #pragma unroll
            for (int pp = 0; pp < 4; ++pp) {
                const int row = pp * 32 + srow;
                *reinterpret_cast<uint4*>(As[nb] + row * 128 + (scolB ^ ((row & 7) << 4))) = sv[pp];
            }
        }
    }

    #pragma unroll
    for (int mt = 0; mt < 4; ++mt)
        #pragma unroll
        for (int nt = 0; nt < 4; ++nt) {
            const int col = wn * 64 + nt * 16 + l15;
            if (col < 100) {
                #pragma unroll
                for (int r = 0; r < 4; ++r) {
                    const int row = mb * 128 + wm * 64 + mt * 16 + g * 4 + r;
                    atomicAdd(out + (size_t)row * 100 + col, acc[mt][nt][r]);
                }
            }
        }
}

extern "C" void kernel_launch(void* const* d_in, const int* in_sizes, int n_in,
                              void* d_out, int out_size, void* d_ws, size_t ws_size,
                              hipStream_t stream)
{
    const float* x   = (const float*)d_in[0];
    const float* w1  = (const float*)d_in[1];
    const float* b1  = (const float*)d_in[2];
    const float* g1  = (const float*)d_in[3];
    const float* be1 = (const float*)d_in[4];
    const float* m1  = (const float*)d_in[5];
    const float* v1  = (const float*)d_in[6];
    const float* w2  = (const float*)d_in[7];
    const float* b2  = (const float*)d_in[8];
    const float* g2  = (const float*)d_in[9];
    const float* be2 = (const float*)d_in[10];
    const float* m2  = (const float*)d_in[11];
    const float* v2  = (const float*)d_in[12];
    const float* w3  = (const float*)d_in[13];
    const float* b3  = (const float*)d_in[14];
    const float* g3  = (const float*)d_in[15];
    const float* be3 = (const float*)d_in[16];
    const float* m3  = (const float*)d_in[17];
    const float* v3  = (const float*)d_in[18];
    const float* wf  = (const float*)d_in[19];
    const float* bf  = (const float*)d_in[20];

    __half* hws = (__half*)d_ws;     // 158,821,632 B
    float* out = (float*)d_out;

    k_prep<<<1854, 256, 0, stream>>>(w1, b1, g1, be1, m1, v1,
                                     w2, b2, g2, be2, m2, v2,
                                     w3, b3, g3, be3, m3, v3,
                                     wf, bf, hws, out);
    k_conv123<<<2304, 512, 0, stream>>>(x, hws, hws);
    k_fc<<<792, 256, 0, stream>>>(hws, out);
}

// Round 20
// 229.527 us; speedup vs baseline: 1.1460x; 1.1460x over previous
//
#include <hip/hip_runtime.h>
#include <hip/hip_fp16.h>

#define EPS 1e-5f

typedef _Float16 f16x8 __attribute__((ext_vector_type(8)));
typedef float f32x4 __attribute__((ext_vector_type(4)));
typedef __attribute__((address_space(3))) uint32_t lds_u32;
typedef const __attribute__((address_space(1))) uint32_t glb_u32;

// ---- ws layout (halfs): 158,821,632 B ----
#define WFHT_OFF 0ull               // [kstep32 1936][o 128][kl 32]
#define W2P_OFF 7929856ull          // [kk 18][g 4][co 64][kl8], BN-pre-scaled
#define W3Q_OFF 7966720ull          // [kk 18][g 4][co 128][kl8], BN-pre-scaled
#define H3_OFF  8040448ull          // 1152 x 61952, per patch [co 128][pix 484]
#define FOLD_OFF 79409152ull        // float: [0,576) w1f | [576,640) sh1
                                    // | [640,704) sh2 | [704,832) sh3

__device__ __forceinline__ uint32_t pk2(float a, float b) {
    __half2 h = __floats2half2_rn(a, b);
    return *reinterpret_cast<uint32_t*>(&h);
}

// ---------------- prep: weight repacks (BN-folded) + bias-init (R18, proven) ----------------
__global__ __launch_bounds__(256)
void k_prep(const float* __restrict__ w1, const float* __restrict__ b1,
            const float* __restrict__ g1, const float* __restrict__ be1,
            const float* __restrict__ m1, const float* __restrict__ v1,
            const float* __restrict__ w2, const float* __restrict__ b2,
            const float* __restrict__ g2, const float* __restrict__ be2,
            const float* __restrict__ m2, const float* __restrict__ v2,
            const float* __restrict__ w3, const float* __restrict__ b3,
            const float* __restrict__ g3, const float* __restrict__ be3,
            const float* __restrict__ m3, const float* __restrict__ v3,
            const float* __restrict__ wf, const float* __restrict__ bf,
            __half* __restrict__ ws, float* __restrict__ out)
{
    const int i = blockIdx.x * 256 + threadIdx.x;
    float* fold = reinterpret_cast<float*>(ws + FOLD_OFF);
    if (i < 247808) {                         // wfhT: 1936 ks x 128 o (FC k = wf linear)
        const int ks = i >> 7, o = i & 127;
        uint2 pk[8];
        if (o < 100) {
            const float* src = wf + (size_t)o * 61952 + ks * 32;
            #pragma unroll
            for (int t = 0; t < 8; ++t) {
                const float4 f = *reinterpret_cast<const float4*>(src + 4 * t);
                pk[t] = make_uint2(pk2(f.x, f.y), pk2(f.z, f.w));
            }
        } else {
            #pragma unroll
            for (int t = 0; t < 8; ++t) pk[t] = make_uint2(0u, 0u);
        }
        uint2* dst = reinterpret_cast<uint2*>(ws + WFHT_OFF + (size_t)i * 32);
        #pragma unroll
        for (int t = 0; t < 8; ++t) dst[t] = pk[t];
    } else if (i < 284672) {                  // w2p[kk][g][co64][kl8] * sc2
        const int j = i - 247808;
        const int kk = j >> 11, s = j & 2047;
        const int gg = s >> 9, co = (s >> 3) & 63, kl8 = s & 7;
        const int tap = kk >> 1, ci = (kk & 1) * 32 + gg * 8 + kl8;
        const float sc = g2[co] * rsqrtf(v2[co] + EPS);
        ws[W2P_OFF + j] = __float2half(w2[co * 576 + ci * 9 + tap] * sc);
    } else if (i < 358400) {                  // w3q[kk][g][co128][kl8] * sc3
        const int j = i - 284672;
        const int kk = j >> 12, s = j & 4095;
        const int gg = s >> 10, co = (s >> 3) & 127, kl8 = s & 7;
        const int tap = kk >> 1, ci = (kk & 1) * 32 + gg * 8 + kl8;
        const float sc = g3[co] * rsqrtf(v3[co] + EPS);
        ws[W3Q_OFF + j] = __float2half(w3[co * 576 + ci * 9 + tap] * sc);
    } else if (i < 473600) {                  // out = bias
        const int j = i - 358400;
        out[j] = bf[j % 100];
    } else if (i < 474432) {                  // fold region
        const int j = i - 473600;
        if (j < 576) {
            const int co = j / 9;
            fold[j] = w1[j] * (g1[co] * rsqrtf(v1[co] + EPS));
        } else if (j < 640) {
            const int co = j - 576;
            const float sc = g1[co] * rsqrtf(v1[co] + EPS);
            fold[j] = be1[co] - (m1[co] - b1[co]) * sc;
        } else if (j < 704) {
            const int co = j - 640;
            const float sc = g2[co] * rsqrtf(v2[co] + EPS);
            fold[j] = be2[co] - (m2[co] - b2[co]) * sc;
        } else {
            const int co = j - 704;
            const float sc = g3[co] * rsqrtf(v3[co] + EPS);
            fold[j] = be3[co] - (m3[co] - b3[co]) * sc;
        }
    }
}

// act: 128-B rows (64 fp16), 16B-granule XOR on (row&7)
__device__ __forceinline__ int lds128(int row, int colByte) {
    return row * 128 + (colByte ^ ((row & 7) << 4));
}

// ---------------- fused conv1 -> conv2 -> conv3 (R18, proven 155 us) ----------------
__global__ __launch_bounds__(512, 4)
void k_conv123(const float* __restrict__ x, const __half* __restrict__ ws_c,
               __half* __restrict__ ws)
{
    __shared__ char smem[76400];
    float* patch = reinterpret_cast<float*>(smem);   // 1904 B
    char* act = smem + 1904;                         // 390 x 128 B -> ends 51824
    char* wbuf = smem + 51824;                       // 3 x 8192 B

    const int bid = blockIdx.x;
    const int p = bid >> 1, half = bid & 1;
    const int tid = threadIdx.x, lane = tid & 63, wave = tid >> 6;
    const int l15 = lane & 15, g = lane >> 4;
    const int wm = wave >> 1, wn = wave & 1;
    const int base3 = half * 11;
    const float* fold = reinterpret_cast<const float*>(ws_c + FOLD_OFF);

    // ---- patchify
    {
        const int b = p / 9, r9 = p - b * 9, hb = r9 / 3, wb = r9 - hb * 3;
        const float* xb = x + (size_t)b * 7056 + (hb * 28 + base3) * 84 + wb * 28;
        if (tid < 476) patch[tid] = xb[(tid / 28) * 84 + (tid % 28)];
    }
    __syncthreads();

    // ---- conv1: sliding 3x3 window
    {
        const int co = lane;
        float wr[9];
        #pragma unroll
        for (int t = 0; t < 9; ++t) wr[t] = fold[co * 9 + t];
        const float sh = fold[576 + co];
        #pragma unroll
        for (int rr = 0; rr < 2; ++rr) {
            const int r = wave * 2 + rr;
            if (r < 15) {
                const float* prow = patch + r * 28;
                float a0 = prow[0], a1 = prow[28], a2 = prow[56];
                float b0 = prow[1], b1 = prow[29], b2 = prow[57];
                for (int xp = 0; xp < 13; ++xp) {
                    const int xx = xp * 2;
                    const float2 c0 = *reinterpret_cast<const float2*>(prow + xx + 2);
                    const float2 c1 = *reinterpret_cast<const float2*>(prow + xx + 30);
                    const float2 c2 = *reinterpret_cast<const float2*>(prow + xx + 58);
                    float s = a0 * wr[0] + b0 * wr[1] + c0.x * wr[2]
                            + a1 * wr[3] + b1 * wr[4] + c1.x * wr[5]
                            + a2 * wr[6] + b2 * wr[7] + c2.x * wr[8];
                    *reinterpret_cast<__half*>(act + lds128(r * 26 + xx, co * 2)) =
                        __float2half(fmaxf(s + sh, 0.f));
                    s = b0 * wr[0] + c0.x * wr[1] + c0.y * wr[2]
                      + b1 * wr[3] + c1.x * wr[4] + c1.y * wr[5]
                      + b2 * wr[6] + c2.x * wr[7] + c2.y * wr[8];
                    *reinterpret_cast<__half*>(act + lds128(r * 26 + xx + 1, co * 2)) =
                        __float2half(fmaxf(s + sh, 0.f));
                    a0 = c0.x; a1 = c1.x; a2 = c2.x;
                    b0 = c0.y; b1 = c1.y; b2 = c2.y;
                }
            }
        }
    }
    __syncthreads();

    const __half* w2q = ws_c + W2P_OFF;
    const __half* w3q = ws_c + W3Q_OFF;

    // ---- conv2 (staged): M=312 -> 20 tiles (5/wm); 2 ct per wn. 9 tap-stages.
    int rb2[5];
    #pragma unroll
    for (int t = 0; t < 5; ++t) {
        int m = (wm * 5 + t) * 16 + l15;
        if (m > 311) m = 311;
        const int yy = m / 24, xx = m - yy * 24;
        rb2[t] = yy * 26 + xx;
    }
    f32x4 acc2[5][2];
    #pragma unroll
    for (int t = 0; t < 5; ++t)
        #pragma unroll
        for (int ct = 0; ct < 2; ++ct) acc2[t][ct] = (f32x4)0.f;

    {
        const int w2off = g * 1024 + (wn * 32 + l15) * 16;
        #define STG2(TAP)                                                          \
            __builtin_amdgcn_global_load_lds(                                      \
                (glb_u32*)(w2q + (TAP) * 4096 + wave * 512 + lane * 8),            \
                (lds_u32*)(wbuf + ((TAP) % 3) * 8192 + wave * 1024), 16, 0, 0)
        STG2(0); STG2(1); STG2(2);
        #pragma unroll
        for (int tap = 0; tap < 9; ++tap) {
            if (tap == 0)      asm volatile("s_waitcnt vmcnt(2)" ::: "memory");
            else if (tap < 8)  asm volatile("s_waitcnt vmcnt(1)" ::: "memory");
            else               asm volatile("s_waitcnt vmcnt(0)" ::: "memory");
            __builtin_amdgcn_sched_barrier(0);
            __builtin_amdgcn_s_barrier();
            __builtin_amdgcn_sched_barrier(0);
            if (tap >= 1 && tap <= 6) STG2(tap + 2);
            const char* sb = wbuf + (tap % 3) * 8192;
            const int ro = (tap / 3) * 26 + (tap % 3);
            int ad[5];
            #pragma unroll
            for (int t = 0; t < 5; ++t) ad[t] = lds128(rb2[t] + ro, g * 16);
            #pragma unroll
            for (int par = 0; par < 2; ++par) {
                const f16x8 wv0 = *reinterpret_cast<const f16x8*>(sb + par * 4096 + w2off);
                const f16x8 wv1 = *reinterpret_cast<const f16x8*>(sb + par * 4096 + w2off + 256);
                #pragma unroll
                for (int t = 0; t < 5; ++t) {
                    const f16x8 af = *reinterpret_cast<const f16x8*>(act + (ad[t] ^ (par * 64)));
                    acc2[t][0] = __builtin_amdgcn_mfma_f32_16x16x32_f16(wv0, af, acc2[t][0], 0, 0, 0);
                    acc2[t][1] = __builtin_amdgcn_mfma_f32_16x16x32_f16(wv1, af, acc2[t][1], 0, 0, 0);
                }
            }
        }
        #undef STG2
    }
    __syncthreads();

    // ---- h2 epilogue
    {
        #pragma unroll
        for (int ct = 0; ct < 2; ++ct) {
            const int co0 = wn * 32 + ct * 16 + g * 4;
            const float4 sh4 = *reinterpret_cast<const float4*>(fold + 640 + co0);
            #pragma unroll
            for (int t = 0; t < 5; ++t) {
                const int m = (wm * 5 + t) * 16 + l15;
                if (m < 312) {
                    const float v0 = fmaxf(acc2[t][ct][0] + sh4.x, 0.f);
                    const float v1 = fmaxf(acc2[t][ct][1] + sh4.y, 0.f);
                    const float v2_ = fmaxf(acc2[t][ct][2] + sh4.z, 0.f);
                    const float v3_ = fmaxf(acc2[t][ct][3] + sh4.w, 0.f);
                    *reinterpret_cast<uint2*>(
                        act + lds128(m, wn * 64 + ct * 32 + g * 8)) =
                        make_uint2(pk2(v0, v1), pk2(v2_, v3_));
                }
            }
        }
    }
    __syncthreads();

    // ---- conv3 (staged per kk)
    int rb3[4];
    #pragma unroll
    for (int t = 0; t < 4; ++t) {
        int m = (wm * 4 + t) * 16 + l15;
        if (m > 241) m = 241;
        const int yy = m / 22, xx = m - yy * 22;
        rb3[t] = yy * 24 + xx;
    }
    f32x4 acc3[4][4];
    #pragma unroll
    for (int t = 0; t < 4; ++t)
        #pragma unroll
        for (int ct = 0; ct < 4; ++ct) acc3[t][ct] = (f32x4)0.f;

    {
        const int w3off = g * 2048 + (wn * 64 + l15) * 16;
        #define STG3(KK)                                                           \
            __builtin_amdgcn_global_load_lds(                                      \
                (glb_u32*)(w3q + (KK) * 4096 + wave * 512 + lane * 8),             \
                (lds_u32*)(wbuf + ((KK) % 3) * 8192 + wave * 1024), 16, 0, 0)
        STG3(0); STG3(1); STG3(2);
        #pragma unroll
        for (int tap = 0; tap < 9; ++tap) {
            const int ro = (tap / 3) * 24 + (tap % 3);
            int ad[4];
            #pragma unroll
            for (int t = 0; t < 4; ++t) ad[t] = lds128(rb3[t] + ro, g * 16);
            #pragma unroll
            for (int par = 0; par < 2; ++par) {
                const int kk = tap * 2 + par;
                if (kk == 0)       asm volatile("s_waitcnt vmcnt(2)" ::: "memory");
                else if (kk < 17)  asm volatile("s_waitcnt vmcnt(1)" ::: "memory");
                else               asm volatile("s_waitcnt vmcnt(0)" ::: "memory");
                __builtin_amdgcn_sched_barrier(0);
                __builtin_amdgcn_s_barrier();
                __builtin_amdgcn_sched_barrier(0);
                if (kk >= 1 && kk <= 15) STG3(kk + 2);
                const char* sb = wbuf + (kk % 3) * 8192;
                f16x8 wv[4];
                #pragma unroll
                for (int ct = 0; ct < 4; ++ct)
                    wv[ct] = *reinterpret_cast<const f16x8*>(sb + w3off + ct * 256);
                const int px = par * 64;
                #pragma unroll
                for (int t = 0; t < 4; ++t) {
                    const f16x8 af = *reinterpret_cast<const f16x8*>(act + (ad[t] ^ px));
                    #pragma unroll
                    for (int ct = 0; ct < 4; ++ct)
                        acc3[t][ct] = __builtin_amdgcn_mfma_f32_16x16x32_f16(
                            wv[ct], af, acc3[t][ct], 0, 0, 0);
                }
            }
        }
        #undef STG3
    }

    // ---- h3 epilogue
    {
        __half* slot = ws + H3_OFF + (size_t)p * 61952;
        #pragma unroll
        for (int ct = 0; ct < 4; ++ct) {
            const int co0 = wn * 64 + ct * 16 + g * 4;
            const float4 sh4 = *reinterpret_cast<const float4*>(fold + 704 + co0);
            #pragma unroll
            for (int t = 0; t < 4; ++t) {
                const int m = (wm * 4 + t) * 16 + l15;
                if (m < 242) {
                    const int pixg = 242 * half + m;
                    slot[(size_t)(co0 + 0) * 484 + pixg] =
                        __float2half(fmaxf(acc3[t][ct][0] + sh4.x, 0.f));
                    slot[(size_t)(co0 + 1) * 484 + pixg] =
                        __float2half(fmaxf(acc3[t][ct][1] + sh4.y, 0.f));
                    slot[(size_t)(co0 + 2) * 484 + pixg] =
                        __float2half(fmaxf(acc3[t][ct][2] + sh4.z, 0.f));
                    slot[(size_t)(co0 + 3) * 484 + pixg] =
                        __float2half(fmaxf(acc3[t][ct][3] + sh4.w, 0.f));
                }
            }
        }
    }
}

// ---------------- FC (R18-proven structure) + kc-clustering XCD swizzle ----------------
// Only change vs R18: bijective block remap so each XCD sees a contiguous wgid
// range -> ~6 consecutive kc values (~2.2 MB of wfhT, L2-resident) reused by its
// mb-blocks. Memory pattern per block unchanged.
__global__ __launch_bounds__(256)
void k_fc(const __half* __restrict__ ws, float* __restrict__ out)
{
    const __half* h3 = ws + H3_OFF;
    __shared__ char As[2][16384];          // [64 rows][256 B], XOR-swizzled

    const int bid0 = blockIdx.x;           // 792 = 8 XCDs x 99
    const int wgid = (bid0 & 7) * 99 + (bid0 >> 3);
    const int mb = wgid % 18, kc = wgid / 18;   // kc-major cluster per XCD
    const int tid = threadIdx.x, lane = tid & 63, wave = tid >> 6;
    const int wm = wave >> 1, wn = wave & 1;
    const int l15 = lane & 15, g = lane >> 4;

    const size_t kbase = (size_t)kc * 1408;

    const int srow = tid >> 4;
    const int scolB = (tid & 15) * 16;
    const __half* sbase = h3 + (size_t)(mb * 64) * 61952 + kbase + (tid & 15) * 8;

    const __half* Bp[4];
    #pragma unroll
    for (int nt = 0; nt < 4; ++nt)
        Bp[nt] = ws + WFHT_OFF + (size_t)(kc * 44) * 4096
               + (size_t)(wn * 64 + nt * 16 + l15) * 32 + g * 8;

    f32x4 acc[2][4];
    #pragma unroll
    for (int mt = 0; mt < 2; ++mt)
        #pragma unroll
        for (int nt = 0; nt < 4; ++nt) acc[mt][nt] = (f32x4)0.f;

    {
        uint4 sv[4];
        #pragma unroll
        for (int pp = 0; pp < 4; ++pp)
            sv[pp] = *reinterpret_cast<const uint4*>(sbase + (size_t)(pp * 16 + srow) * 61952);
        #pragma unroll
        for (int pp = 0; pp < 4; ++pp) {
            const int row = pp * 16 + srow;
            *reinterpret_cast<uint4*>(As[0] + row * 256 + (scolB ^ ((row & 7) << 4))) = sv[pp];
        }
    }

    for (int s = 0; s < 11; ++s) {
        __syncthreads();

        uint4 sv[4];
        const int nb = (s + 1) & 1;
        if (s < 10) {
            #pragma unroll
            for (int pp = 0; pp < 4; ++pp)
                sv[pp] = *reinterpret_cast<const uint4*>(
                    sbase + (size_t)(pp * 16 + srow) * 61952 + (s + 1) * 128);
        }

        const char* Ab = As[s & 1];
        #pragma unroll
        for (int kk = 0; kk < 4; ++kk) {
            f16x8 a[2];
            #pragma unroll
            for (int mt = 0; mt < 2; ++mt) {
                const int row = wm * 32 + mt * 16 + l15;
                a[mt] = *reinterpret_cast<const f16x8*>(
                    Ab + row * 256 + ((kk * 64 + g * 16) ^ ((row & 7) << 4)));
            }
            f16x8 b[4];
            #pragma unroll
            for (int nt = 0; nt < 4; ++nt)
                b[nt] = *reinterpret_cast<const f16x8*>(Bp[nt] + (s * 4 + kk) * 4096);
            #pragma unroll
            for (int nt = 0; nt < 4; ++nt) {
                acc[0][nt] = __builtin_amdgcn_mfma_f32_16x16x32_f16(a[0], b[nt], acc[0][nt], 0, 0, 0);
                acc[1][nt] = __builtin_amdgcn_mfma_f32_16x16x32_f16(a[1], b[nt], acc[1][nt], 0, 0, 0);
            }
        }

        if (s < 10) {
            #pragma unroll
            for (int pp = 0; pp < 4; ++pp) {
                const int row = pp * 16 + srow;
                *reinterpret_cast<uint4*>(As[nb] + row * 256 + (scolB ^ ((row & 7) << 4))) = sv[pp];
            }
        }
    }

    #pragma unroll
    for (int mt = 0; mt < 2; ++mt)
        #pragma unroll
        for (int nt = 0; nt < 4; ++nt) {
            const int col = wn * 64 + nt * 16 + l15;
            if (col < 100) {
                #pragma unroll
                for (int r = 0; r < 4; ++r) {
                    const int row = mb * 64 + wm * 32 + mt * 16 + g * 4 + r;
                    atomicAdd(out + (size_t)row * 100 + col, acc[mt][nt][r]);
                }
            }
        }
}

extern "C" void kernel_launch(void* const* d_in, const int* in_sizes, int n_in,
                              void* d_out, int out_size, void* d_ws, size_t ws_size,
                              hipStream_t stream)
{
    const float* x   = (const float*)d_in[0];
    const float* w1  = (const float*)d_in[1];
    const float* b1  = (const float*)d_in[2];
    const float* g1  = (const float*)d_in[3];
    const float* be1 = (const float*)d_in[4];
    const float* m1  = (const float*)d_in[5];
    const float* v1  = (const float*)d_in[6];
    const float* w2  = (const float*)d_in[7];
    const float* b2  = (const float*)d_in[8];
    const float* g2  = (const float*)d_in[9];
    const float* be2 = (const float*)d_in[10];
    const float* m2  = (const float*)d_in[11];
    const float* v2  = (const float*)d_in[12];
    const float* w3  = (const float*)d_in[13];
    const float* b3  = (const float*)d_in[14];
    const float* g3  = (const float*)d_in[15];
    const float* be3 = (const float*)d_in[16];
    const float* m3  = (const float*)d_in[17];
    const float* v3  = (const float*)d_in[18];
    const float* wf  = (const float*)d_in[19];
    const float* bf  = (const float*)d_in[20];

    __half* hws = (__half*)d_ws;     // 158,821,632 B
    float* out = (float*)d_out;

    k_prep<<<1854, 256, 0, stream>>>(w1, b1, g1, be1, m1, v1,
                                     w2, b2, g2, be2, m2, v2,
                                     w3, b3, g3, be3, m3, v3,
                                     wf, bf, hws, out);
    k_conv123<<<2304, 512, 0, stream>>>(x, hws, hws);
    k_fc<<<792, 256, 0, stream>>>(hws, out);
}